// Round 4
// baseline (12.219 us; speedup 1.0000x reference)
//
#include <hip/hip_runtime.h>

// Closed-form Pauli contraction, v4: transfer-matrix DP (full 243-term sum in
// ~115 complex mults), one thread per sample, single code path, no barriers
// after parameter setup.
//
// Frame (inherited, harness-verified since the statevector kernel): after
// folding layer-1 CNOTs into a GF(2) index remap, |psi> is a PRODUCT state
// over 9 physical bits (bit m holds qubit q = 8-m), and the conjugated
// observable is
//   O = prod_{p in {8,7,5,3,1}} h^(p),
//   h^(p) = al_p Z_{u_p} + br_p X_{w_p} + i bi_p Z_{u_p} X_{w_p},
// u_p . w_q = delta_pq. Expanding into 3^5 Pauli terms Z_U X_W (trit c_p:
// 0->Z coeff al, 1->X coeff br, 2->ZX coeff i*bi), the product-state
// expectation factors per bit: <Z^u X^w> = 1 / z / x / i*y, with the per-bit
// (U_m, W_m) staircase
//   m=0:(a8,b1) m=1:(t1,b1) m=2:(t1,b3) m=3:(t3,b3) m=4:(t3,b5)
//   m=5:(t5,b5) m=6:(t5,b7) m=7:(t5^a7,b7^b8) m=8:(t5^a8^a7,b8),
//   t1=a8^a1, t3=t1^a3, t5=t3^a5.
//
// v4 refactor (pure associativity, entry-checked against the verified
// 4-level DP): levels 5 and 3 are c8-INDEPENDENT 2x2 complex transfer
// matrices
//   M5[t3][t3]   = K5_X  F4[t3][1] F5[t3][1]
//   M5[t3][t3^1] = K5_Z  F4[t3][0] F5[t3^1][0] + K5_ZX F4[t3][1] F5[t3^1][1]
// (M3 analogous with F2,F3), and level 1 is a pair of row vectors
//   R[a8][a8]    = K1_X  F0[a8][1] F1[a8][1]
//   R[a8][a8^1]  = K1_Z  F0[a8][0] F1[a8^1][0] + K1_ZX F0[a8][1] F1[a8^1][1].
// Then E = sum_c8 Re{ K8[c8] * (R[a8(c8)] . M3 . M5 . S7col(c8)) } with
// S7[t5][c8] the verified level-7 sum. Levels 5/3/1 are computed ONCE
// instead of per-c8: full sum in ~115 cmul vs ~130 for v2's 2/3 slice.
//
// v3 post-mortem folded in: 3 divergent unrolled DP bodies + 3-wave blocks
// REGRESSED (11.4 us) -> single code path, no inter-wave coupling, 128
// blocks of 256 threads.

#if defined(__clang__)
#pragma float_control(precise, off)   // fold the structural 0/1 components
#endif

struct C2 { float r, i; };
__device__ __forceinline__ C2 cmul(C2 a, C2 b) {
    return C2{a.r * b.r - a.i * b.i, a.r * b.i + a.i * b.r};
}
__device__ __forceinline__ C2 cadd(C2 a, C2 b) { return C2{a.r + b.r, a.i + b.i}; }

__global__ __launch_bounds__(256) void qsim_kernel(const float* __restrict__ x,
                                                   const float* __restrict__ w,
                                                   float* __restrict__ out,
                                                   int nsamples) {
    __shared__ float cb[9][6];   // per qubit: {Cz_z, Cy_z, Cz_x, Cy_x, Cz_y, Cy_y}
    __shared__ float hm[5][3];   // h params for p = 8,7,5,3,1: {alpha, beta_r, beta_i}
    const int tid = threadIdx.x;
    if (tid < 9) {
        const int q = tid;
        const float phi = w[q * 3 + 0], theta = w[q * 3 + 1], omega = w[q * 3 + 2];
        float st, ct, sp, cp, sm, cm;
        __sincosf(0.5f * theta, &st, &ct);
        __sincosf(0.5f * (phi + omega), &sp, &cp);
        __sincosf(0.5f * (phi - omega), &sm, &cm);
        const float m00r =  cp * ct, m00i = -sp * ct;
        const float m01r = -cm * st, m01i = -sm * st;
        const float m10r =  cm * st, m10i = -sm * st;
        const float m11r =  cp * ct, m11i =  sp * ct;
        // Cz = Bloch(U|0>) = Bloch((m00, m10)), components (z, x, y)
        cb[q][0] = (m00r * m00r + m00i * m00i) - (m10r * m10r + m10i * m10i);
        cb[q][2] = 2.0f * (m00r * m10r + m00i * m10i);
        cb[q][4] = 2.0f * (m00r * m10i - m00i * m10r);
        // Cy = Bloch(U|y+>), |y+> = (|0>+i|1>)/sqrt2 -> u = (m00+i*m01, m10+i*m11)/sqrt2
        const float u0r = m00r - m01i, u0i = m00i + m01r;
        const float u1r = m10r - m11i, u1i = m10i + m11r;
        cb[q][1] = 0.5f * ((u0r * u0r + u0i * u0i) - (u1r * u1r + u1i * u1i));
        cb[q][3] = (u0r * u1r + u0i * u1i);
        cb[q][5] = (u0r * u1i - u0i * u1r);
    } else if (tid >= 16 && tid < 21) {
        const int i = tid - 16;
        const int qs[5] = {0, 1, 3, 5, 7};  // wire q; logical p = 8,7,5,3,1
        const int q = qs[i];
        const float phi = w[27 + q * 3 + 0], theta = w[27 + q * 3 + 1];
        float stt, ctt, sf, cf;
        __sincosf(theta, &stt, &ctt);
        __sincosf(phi, &sf, &cf);
        hm[i][0] = ctt;          // alpha = cos(theta)
        hm[i][1] = -stt * cf;    // beta  = -sin(theta) e^{i phi}
        hm[i][2] = -stt * sf;
    }
    __syncthreads();

    const int n = (blockIdx.x << 8) + tid;   // one sample per thread
    if (n >= nsamples) return;
    const int b  = n >> 12;
    const int i0 = (n >> 6) & 63;
    const int j0 = n & 63;                   // lane == column -> coalesced loads

    // --- Bloch components per physical bit m (qubit q = 8 - m):
    //     Bloch(U_q RX(a)|0>) = cos(a) * Cz_q - sin(a) * Cy_q ---
    float Zb[9], Xb[9], Yb[9];
    #pragma unroll
    for (int ki = 0; ki < 3; ++ki) {
        #pragma unroll
        for (int kj = 0; kj < 3; ++kj) {
            const int q = ki * 3 + kj;
            const int m = 8 - q;
            const int ii = i0 + ki - 1, jj = j0 + kj - 1;
            // branch-free: wrapped address is always in-bounds; mask after
            const bool ok = ((unsigned)ii < 64u) & ((unsigned)jj < 64u);
            float a = x[(b << 12) + ((ii & 63) << 6) + (jj & 63)];
            a = ok ? a : 0.0f;
            float sa, ca;
            __sincosf(a, &sa, &ca);
            Zb[m] = ca * cb[q][0] - sa * cb[q][1];
            Xb[m] = ca * cb[q][2] - sa * cb[q][3];
            Yb[m] = ca * cb[q][4] - sa * cb[q][5];
        }
    }

    // per-bit complex Pauli factors F[m][U][W]; structural zeros fold at -O3
    C2 F[9][2][2];
    #pragma unroll
    for (int m = 0; m < 9; ++m) {
        F[m][0][0] = C2{1.0f, 0.0f};
        F[m][1][0] = C2{Zb[m], 0.0f};
        F[m][0][1] = C2{Xb[m], 0.0f};
        F[m][1][1] = C2{0.0f, Yb[m]};
    }
    // choice coefficients: slot 0=p8, 1=p7, 2=p5, 3=p3, 4=p1
    C2 K[5][3];
    #pragma unroll
    for (int i = 0; i < 5; ++i) {
        K[i][0] = C2{hm[i][0], 0.0f};   // alpha  (Z)
        K[i][1] = C2{hm[i][1], 0.0f};   // br     (X)
        K[i][2] = C2{0.0f, hm[i][2]};   // i*bi   (ZX)
    }
    const int A[3] = {1, 0, 1};
    const int B[3] = {0, 1, 1};

    // ---- level 7 (verified recurrence): S7[t5][c8], bits 6,7,8 ----
    C2 S7[2][3];
    #pragma unroll
    for (int t5 = 0; t5 < 2; ++t5) {
        #pragma unroll
        for (int c8 = 0; c8 < 3; ++c8) {
            const int a8 = A[c8], b8 = B[c8];
            C2 acc = C2{0.0f, 0.0f};
            #pragma unroll
            for (int c7 = 0; c7 < 3; ++c7) {
                const int a7 = A[c7], b7 = B[c7];
                C2 v = cmul(K[1][c7], F[6][t5][b7]);
                v = cmul(v, F[7][t5 ^ a7][b7 ^ b8]);
                v = cmul(v, F[8][t5 ^ a8 ^ a7][b8]);
                acc = cadd(acc, v);
            }
            S7[t5][c8] = acc;
        }
    }

    // ---- c8-independent transfer matrices (levels 5 and 3, computed ONCE) ----
    C2 M5[2][2], M3[2][2];
    #pragma unroll
    for (int t = 0; t < 2; ++t) {
        M5[t][t]     = cmul(K[2][1], cmul(F[4][t][1], F[5][t][1]));
        M5[t][t ^ 1] = cadd(cmul(K[2][0], cmul(F[4][t][0], F[5][t ^ 1][0])),
                            cmul(K[2][2], cmul(F[4][t][1], F[5][t ^ 1][1])));
        M3[t][t]     = cmul(K[3][1], cmul(F[2][t][1], F[3][t][1]));
        M3[t][t ^ 1] = cadd(cmul(K[3][0], cmul(F[2][t][0], F[3][t ^ 1][0])),
                            cmul(K[3][2], cmul(F[2][t][1], F[3][t ^ 1][1])));
    }
    // ---- level-1 row vectors over a8 ----
    C2 R[2][2];
    #pragma unroll
    for (int a8 = 0; a8 < 2; ++a8) {
        R[a8][a8]     = cmul(K[4][1], cmul(F[0][a8][1], F[1][a8][1]));
        R[a8][a8 ^ 1] = cadd(cmul(K[4][0], cmul(F[0][a8][0], F[1][a8 ^ 1][0])),
                             cmul(K[4][2], cmul(F[0][a8][1], F[1][a8 ^ 1][1])));
    }
    // ---- V[a8] = (R[a8] . M3) . M5 ----
    C2 V[2][2];
    #pragma unroll
    for (int a8 = 0; a8 < 2; ++a8) {
        C2 rm[2];
        #pragma unroll
        for (int t3 = 0; t3 < 2; ++t3)
            rm[t3] = cadd(cmul(R[a8][0], M3[0][t3]), cmul(R[a8][1], M3[1][t3]));
        #pragma unroll
        for (int t5 = 0; t5 < 2; ++t5)
            V[a8][t5] = cadd(cmul(rm[0], M5[0][t5]), cmul(rm[1], M5[1][t5]));
    }
    // ---- close over c8 (every complete term is real) ----
    float E = 0.0f;
    #pragma unroll
    for (int c8 = 0; c8 < 3; ++c8) {
        const int a8 = A[c8];
        C2 acc = cadd(cmul(V[a8][0], S7[0][c8]), cmul(V[a8][1], S7[1][c8]));
        E += K[0][c8].r * acc.r - K[0][c8].i * acc.i;
    }
    out[n] = E;
}

extern "C" void kernel_launch(void* const* d_in, const int* in_sizes, int n_in,
                              void* d_out, int out_size, void* d_ws, size_t ws_size,
                              hipStream_t stream) {
    const float* x = (const float*)d_in[0];   // (8,1,64,64) float32
    const float* w = (const float*)d_in[1];   // (2,9,3) float32
    float* out = (float*)d_out;               // 32768 float32
    const int nsamples = out_size;
    const int blocks = (nsamples + 255) >> 8; // 128 blocks x 256 threads
    qsim_kernel<<<blocks, 256, 0, stream>>>(x, w, out, nsamples);
}

// Round 5
// 9.439 us; speedup vs baseline: 1.2946x; 1.2946x over previous
//
#include <hip/hip_runtime.h>

// Closed-form Pauli contraction, v5 = v2 champion structure + v4-verified
// transfer-matrix DP core.
//
// Frame (inherited, harness-verified since the statevector kernel): after
// folding layer-1 CNOTs into a GF(2) index remap, |psi> is a PRODUCT state
// over 9 physical bits (bit m holds qubit q = 8-m), and the conjugated
// observable is
//   O = prod_{p in {8,7,5,3,1}} h^(p),
//   h^(p) = al_p Z_{u_p} + br_p X_{w_p} + i bi_p Z_{u_p} X_{w_p},
// u_p . w_q = delta_pq. Expanding into 3^5 Pauli terms Z_U X_W (trit c_p:
// 0->Z coeff al, 1->X coeff br, 2->ZX coeff i*bi), the product-state
// expectation factors per bit: <Z^u X^w> = 1 / z / x / i*y, with the per-bit
// (U_m, W_m) staircase
//   m=0:(a8,b1) m=1:(t1,b1) m=2:(t1,b3) m=3:(t3,b3) m=4:(t3,b5)
//   m=5:(t5,b5) m=6:(t5,b7) m=7:(t5^a7,b7^b8) m=8:(t5^a8^a7,b8),
//   t1=a8^a1, t3=t1^a3, t5=t3^a5.
//
// Measured session ladder: v0 statevector 40.5 | v1 thread/sample 9.84 |
// v2 2-wave c8 split 9.40 (CHAMPION) | v3 3-wave 11.42 (REGRESSED: 3
// divergent unrolled bodies) | v4 transfer-matrix @128 blocks 12.22
// (REGRESSED: half-machine block count). Model: dur = ~8.4us launch floor +
// kernel (v2 ~0.9us). v5 keeps v2's structure byte-for-byte (512 blocks x
// 128 threads, 2 waves on the same 64 samples, c8 split 1-vs-2, LDS partial
// combine) and swaps only the DP slice evaluator for the transfer-matrix
// form v4 verified (levels 5/3/1 as c8-independent 2x2 complex transfer
// matrices; per-c8 marginal cost = one S7 column + R.G.S7col):
//   M5[t][t]   = K5_X  F4[t][1] F5[t][1]
//   M5[t][t^1] = K5_Z  F4[t][0] F5[t^1][0] + K5_ZX F4[t][1] F5[t^1][1]
//   (M3 analogous with F2,F3; R rows analogous with F0,F1; G = M3.M5)
//   E = sum_c8 Re{ K8[c8] * (R[a8(c8)] . G . S7col(c8)) }.
// Cuts ~25% off wave 1's critical path vs v2's per-c8 level recomputation,
// with strictly smaller code.

#if defined(__clang__)
#pragma float_control(precise, off)   // fold the structural 0/1 components
#endif

struct C2 { float r, i; };
__device__ __forceinline__ C2 cmul(C2 a, C2 b) {
    return C2{a.r * b.r - a.i * b.i, a.r * b.i + a.i * b.r};
}
__device__ __forceinline__ C2 cadd(C2 a, C2 b) { return C2{a.r + b.r, a.i + b.i}; }

// Transfer-matrix DP over the c8-slice [C8BASE, C8BASE+NC8).
template<int C8BASE, int NC8>
__device__ __forceinline__ float dp_eval_tm(const float (&Zb)[9], const float (&Xb)[9],
                                            const float (&Yb)[9], const float (&hm)[5][3]) {
    // per-bit complex Pauli factors F[m][U][W]; structural zeros fold at -O3
    C2 F[9][2][2];
    #pragma unroll
    for (int m = 0; m < 9; ++m) {
        F[m][0][0] = C2{1.0f, 0.0f};
        F[m][1][0] = C2{Zb[m], 0.0f};
        F[m][0][1] = C2{Xb[m], 0.0f};
        F[m][1][1] = C2{0.0f, Yb[m]};
    }
    // choice coefficients: slot 0=p8, 1=p7, 2=p5, 3=p3, 4=p1
    C2 K[5][3];
    #pragma unroll
    for (int i = 0; i < 5; ++i) {
        K[i][0] = C2{hm[i][0], 0.0f};   // alpha  (Z)
        K[i][1] = C2{hm[i][1], 0.0f};   // br     (X)
        K[i][2] = C2{0.0f, hm[i][2]};   // i*bi   (ZX)
    }
    const int A[3] = {1, 0, 1};
    const int B[3] = {0, 1, 1};

    // ---- level 7 (verified recurrence): S7 columns for this slice ----
    C2 S7[2][NC8];
    #pragma unroll
    for (int t5 = 0; t5 < 2; ++t5) {
        #pragma unroll
        for (int c8i = 0; c8i < NC8; ++c8i) {
            const int c8 = C8BASE + c8i;
            const int a8 = A[c8], b8 = B[c8];
            C2 acc = C2{0.0f, 0.0f};
            #pragma unroll
            for (int c7 = 0; c7 < 3; ++c7) {
                const int a7 = A[c7], b7 = B[c7];
                C2 v = cmul(K[1][c7], F[6][t5][b7]);
                v = cmul(v, F[7][t5 ^ a7][b7 ^ b8]);
                v = cmul(v, F[8][t5 ^ a8 ^ a7][b8]);
                acc = cadd(acc, v);
            }
            S7[t5][c8i] = acc;
        }
    }

    // ---- c8-independent transfer matrices (levels 5, 3) and row vectors ----
    C2 M5[2][2], M3[2][2], R[2][2];
    #pragma unroll
    for (int t = 0; t < 2; ++t) {
        M5[t][t]     = cmul(K[2][1], cmul(F[4][t][1], F[5][t][1]));
        M5[t][t ^ 1] = cadd(cmul(K[2][0], cmul(F[4][t][0], F[5][t ^ 1][0])),
                            cmul(K[2][2], cmul(F[4][t][1], F[5][t ^ 1][1])));
        M3[t][t]     = cmul(K[3][1], cmul(F[2][t][1], F[3][t][1]));
        M3[t][t ^ 1] = cadd(cmul(K[3][0], cmul(F[2][t][0], F[3][t ^ 1][0])),
                            cmul(K[3][2], cmul(F[2][t][1], F[3][t ^ 1][1])));
        R[t][t]      = cmul(K[4][1], cmul(F[0][t][1], F[1][t][1]));
        R[t][t ^ 1]  = cadd(cmul(K[4][0], cmul(F[0][t][0], F[1][t ^ 1][0])),
                            cmul(K[4][2], cmul(F[0][t][1], F[1][t ^ 1][1])));
    }
    // ---- G = M3 . M5 (unused entries/rows DCE'd per template instance) ----
    C2 G[2][2];
    #pragma unroll
    for (int i = 0; i < 2; ++i)
        #pragma unroll
        for (int j = 0; j < 2; ++j)
            G[i][j] = cadd(cmul(M3[i][0], M5[0][j]), cmul(M3[i][1], M5[1][j]));

    // ---- close: E = sum_c8 Re{ K8[c8] * (R[a8] . G . S7col) } ----
    float E = 0.0f;
    #pragma unroll
    for (int c8i = 0; c8i < NC8; ++c8i) {
        const int c8 = C8BASE + c8i;
        const int a8 = A[c8];
        const C2 v0 = cadd(cmul(R[a8][0], G[0][0]), cmul(R[a8][1], G[1][0]));
        const C2 v1 = cadd(cmul(R[a8][0], G[0][1]), cmul(R[a8][1], G[1][1]));
        const C2 acc = cadd(cmul(v0, S7[0][c8i]), cmul(v1, S7[1][c8i]));
        E += K[0][c8].r * acc.r - K[0][c8].i * acc.i;
    }
    return E;
}

__global__ __launch_bounds__(128) void qsim_kernel(const float* __restrict__ x,
                                                   const float* __restrict__ w,
                                                   float* __restrict__ out,
                                                   int nsamples) {
    __shared__ float cb[9][6];   // per qubit: {Cz_z, Cy_z, Cz_x, Cy_x, Cz_y, Cy_y}
    __shared__ float hm[5][3];   // h params for p = 8,7,5,3,1: {alpha, beta_r, beta_i}
    __shared__ float part[64];   // wave-1 partials
    const int tid = threadIdx.x;
    if (tid < 9) {
        const int q = tid;
        const float phi = w[q * 3 + 0], theta = w[q * 3 + 1], omega = w[q * 3 + 2];
        float st, ct, sp, cp, sm, cm;
        __sincosf(0.5f * theta, &st, &ct);
        __sincosf(0.5f * (phi + omega), &sp, &cp);
        __sincosf(0.5f * (phi - omega), &sm, &cm);
        const float m00r =  cp * ct, m00i = -sp * ct;
        const float m01r = -cm * st, m01i = -sm * st;
        const float m10r =  cm * st, m10i = -sm * st;
        const float m11r =  cp * ct, m11i =  sp * ct;
        // Cz = Bloch(U|0>) = Bloch((m00, m10)), components (z, x, y)
        cb[q][0] = (m00r * m00r + m00i * m00i) - (m10r * m10r + m10i * m10i);
        cb[q][2] = 2.0f * (m00r * m10r + m00i * m10i);
        cb[q][4] = 2.0f * (m00r * m10i - m00i * m10r);
        // Cy = Bloch(U|y+>), |y+> = (|0>+i|1>)/sqrt2 -> u = (m00+i*m01, m10+i*m11)/sqrt2
        const float u0r = m00r - m01i, u0i = m00i + m01r;
        const float u1r = m10r - m11i, u1i = m10i + m11r;
        cb[q][1] = 0.5f * ((u0r * u0r + u0i * u0i) - (u1r * u1r + u1i * u1i));
        cb[q][3] = (u0r * u1r + u0i * u1i);
        cb[q][5] = (u0r * u1i - u0i * u1r);
    } else if (tid >= 16 && tid < 21) {
        const int i = tid - 16;
        const int qs[5] = {0, 1, 3, 5, 7};  // wire q; logical p = 8,7,5,3,1
        const int q = qs[i];
        const float phi = w[27 + q * 3 + 0], theta = w[27 + q * 3 + 1];
        float stt, ctt, sf, cf;
        __sincosf(theta, &stt, &ctt);
        __sincosf(phi, &sf, &cf);
        hm[i][0] = ctt;          // alpha = cos(theta)
        hm[i][1] = -stt * cf;    // beta  = -sin(theta) e^{i phi}
        hm[i][2] = -stt * sf;
    }
    __syncthreads();

    const int lane = tid & 63;
    const int half = tid >> 6;               // wave id in block (uniform per wave)
    const int n = (blockIdx.x << 6) + lane;  // both waves own the same 64 samples

    float E = 0.0f;
    if (n < nsamples) {
        const int b  = n >> 12;
        const int i0 = (n >> 6) & 63;
        const int j0 = n & 63;               // lane == column -> coalesced loads

        // Bloch components per physical bit m (qubit q = 8 - m):
        // Bloch(U_q RX(a)|0>) = cos(a) * Cz_q - sin(a) * Cy_q
        float Zb[9], Xb[9], Yb[9];
        #pragma unroll
        for (int ki = 0; ki < 3; ++ki) {
            #pragma unroll
            for (int kj = 0; kj < 3; ++kj) {
                const int q = ki * 3 + kj;
                const int m = 8 - q;
                const int ii = i0 + ki - 1, jj = j0 + kj - 1;
                float a = 0.0f;
                if (ii >= 0 && ii < 64 && jj >= 0 && jj < 64)
                    a = x[(b << 12) + (ii << 6) + jj];
                float sa, ca;
                __sincosf(a, &sa, &ca);
                Zb[m] = ca * cb[q][0] - sa * cb[q][1];
                Xb[m] = ca * cb[q][2] - sa * cb[q][3];
                Yb[m] = ca * cb[q][4] - sa * cb[q][5];
            }
        }
        if (half == 0) E = dp_eval_tm<0, 1>(Zb, Xb, Yb, hm);  // c8 = 0 slice
        else           E = dp_eval_tm<1, 2>(Zb, Xb, Yb, hm);  // c8 in {1,2} slice
    }
    if (half) part[lane] = E;
    __syncthreads();
    if (!half && n < nsamples) out[n] = E + part[lane];
}

extern "C" void kernel_launch(void* const* d_in, const int* in_sizes, int n_in,
                              void* d_out, int out_size, void* d_ws, size_t ws_size,
                              hipStream_t stream) {
    const float* x = (const float*)d_in[0];   // (8,1,64,64) float32
    const float* w = (const float*)d_in[1];   // (2,9,3) float32
    float* out = (float*)d_out;               // 32768 float32
    const int nsamples = out_size;
    const int blocks = (nsamples + 63) >> 6;  // 64 samples per 128-thread block
    qsim_kernel<<<blocks, 128, 0, stream>>>(x, w, out, nsamples);
}